// Round 8
// baseline (298.300 us; speedup 1.0000x reference)
//
#include <hip/hip_runtime.h>
#include <hip/hip_bf16.h>
#include <math.h>

#define S_LEN 4096
#define EMB   1024
#define NHEAD 16
#define HDIM  64

typedef __attribute__((ext_vector_type(8))) _Float16 half8;
typedef __attribute__((ext_vector_type(4))) _Float16 half4;
typedef __attribute__((ext_vector_type(4))) float float4_t;
typedef __attribute__((ext_vector_type(16))) float float16_t;
typedef __attribute__((ext_vector_type(4))) int int4_t;
typedef __attribute__((ext_vector_type(2))) int int2_t;

#define GLOBAL_AS(p) ((const __attribute__((address_space(1))) void*)(p))
#define LDS_AS(p)    ((__attribute__((address_space(3))) void*)(p))

#define LOG2E 1.4426950408889634f

// ---------------------------------------------------------------------------
// fused prep: blocks [0,4096) convert x fp32->fp16; [4096,4864) transpose
// Wqkv [1024,3072] -> WTh [3072,1024]; [4864,5120) transpose Wp -> WpT.
// ---------------------------------------------------------------------------
__global__ __launch_bounds__(256) void prep(
    const float* __restrict__ x, const float* __restrict__ Wqkv,
    const float* __restrict__ Wp,
    _Float16* __restrict__ xh, _Float16* __restrict__ WTh,
    _Float16* __restrict__ WpT)
{
    const int bid = blockIdx.x;
    if (bid < 4096) {
        const int i = bid * 256 + threadIdx.x;
        const float4_t v = ((const float4_t*)x)[i];
        half4 hh;
#pragma unroll
        for (int j = 0; j < 4; ++j) hh[j] = (_Float16)v[j];
        ((half4*)xh)[i] = hh;
        return;
    }
    __shared__ float t[64][65];
    const float* in;
    _Float16* out;
    int R, C, bx, by;
    if (bid < 4096 + 768) {
        const int idx = bid - 4096;
        bx = idx % 48; by = idx / 48;
        in = Wqkv; out = WTh; R = 1024; C = 3072;
    } else {
        const int idx = bid - 4864;
        bx = idx & 15; by = idx >> 4;
        in = Wp; out = WpT; R = 1024; C = 1024;
    }
    const int r0 = by * 64, c0 = bx * 64;
    for (int i = threadIdx.x; i < 64 * 64; i += 256) {
        int r = i >> 6, c = i & 63;
        t[r][c] = in[(size_t)(r0 + r) * C + c0 + c];
    }
    __syncthreads();
    for (int i = threadIdx.x; i < 64 * 64; i += 256) {
        int c = i >> 6, r = i & 63;
        out[(size_t)(c0 + c) * R + r0 + r] = (_Float16)t[r][c];
    }
}

// ---------------------------------------------------------------------------
// QKV GEMM, plain fp16, m97 structure: 128x128 tile, BK=32, global_load_lds.
// Epilogue: cols<1024 -> q plane; 1024..2047 -> k plane SCALED by log2(e);
// cols>=2048 -> fp16 V^T [1024,4096], packed half4 along s.
// ---------------------------------------------------------------------------
__global__ __launch_bounds__(256) void gemm_qkv(
    const _Float16* __restrict__ Ag, const _Float16* __restrict__ Bg,
    const float* __restrict__ bias,
    _Float16* __restrict__ qk, _Float16* __restrict__ vt, int K)
{
    constexpr int BK = 32;
    __shared__ _Float16 Ah[128 * BK];
    __shared__ _Float16 Bh[128 * BK];

    const int tid = threadIdx.x;
    const int wave = tid >> 6, lane = tid & 63;
    const int l16 = lane & 15, quad = lane >> 4;
    const int wr = wave >> 1, wc = wave & 1;
    const int row0 = blockIdx.y * 128, col0 = blockIdx.x * 128;
    const int lrow = lane >> 2, lc8 = (lane & 3) * 8;

    float4_t acc[4][4];
#pragma unroll
    for (int i = 0; i < 4; ++i)
#pragma unroll
        for (int j = 0; j < 4; ++j) acc[i][j] = (float4_t){0.f, 0.f, 0.f, 0.f};

    for (int k0 = 0; k0 < K; k0 += BK) {
        __syncthreads();
#pragma unroll
        for (int i = 0; i < 2; ++i) {
            const int ar = i * 64 + wave * 16;
            __builtin_amdgcn_global_load_lds(
                GLOBAL_AS(Ag + (size_t)(row0 + ar + lrow) * K + k0 + lc8),
                LDS_AS(&Ah[ar * BK]), 16, 0, 0);
            __builtin_amdgcn_global_load_lds(
                GLOBAL_AS(Bg + (size_t)(col0 + ar + lrow) * K + k0 + lc8),
                LDS_AS(&Bh[ar * BK]), 16, 0, 0);
        }
        __syncthreads();

        half8 af[4], bfr[4];
#pragma unroll
        for (int t = 0; t < 4; ++t) {
            af[t]  = *(const half8*)&Ah[(wr * 64 + t * 16 + l16) * BK + quad * 8];
            bfr[t] = *(const half8*)&Bh[(wc * 64 + t * 16 + l16) * BK + quad * 8];
        }
#pragma unroll
        for (int i = 0; i < 4; ++i)
#pragma unroll
            for (int j = 0; j < 4; ++j)
                acc[i][j] = __builtin_amdgcn_mfma_f32_16x16x32_f16(af[i], bfr[j], acc[i][j], 0, 0, 0);
    }

#pragma unroll
    for (int i = 0; i < 4; ++i) {
#pragma unroll
        for (int j = 0; j < 4; ++j) {
            const int colb = col0 + wc * 64 + j * 16 + l16;
            const float bv = bias[colb];
            const int rowb = row0 + wr * 64 + i * 16 + quad * 4;
            if (colb < 2048) {
                const float sc = (colb >= 1024) ? LOG2E : 1.0f;
#pragma unroll
                for (int r = 0; r < 4; ++r)
                    qk[(size_t)(rowb + r) * 2048 + colb] =
                        (_Float16)((acc[i][j][r] + bv) * sc);
            } else {
                half4 w;
#pragma unroll
                for (int r = 0; r < 4; ++r) w[r] = (_Float16)(acc[i][j][r] + bv);
                *(half4*)&vt[(size_t)(colb - 2048) * 4096 + rowb] = w;
            }
        }
    }
}

// ---------------------------------------------------------------------------
// Out-projection GEMM, fp16, 128(M)x64(N) tile -> 512 blocks (2/CU; was 256
// = 1/CU latency-bound). 4 waves: wave owns 32 M-rows x full 64 N.
// ---------------------------------------------------------------------------
__global__ __launch_bounds__(256) void gemm_out(
    const _Float16* __restrict__ Ag, const _Float16* __restrict__ Bg,
    const float* __restrict__ bias, float* __restrict__ C, int N, int K)
{
    constexpr int BK = 32;
    __shared__ _Float16 Ah[128 * BK];
    __shared__ _Float16 Bh[64 * BK];

    const int tid = threadIdx.x;
    const int wave = tid >> 6, lane = tid & 63;
    const int l16 = lane & 15, quad = lane >> 4;
    const int row0 = blockIdx.y * 128, col0 = blockIdx.x * 64;
    const int lrow = lane >> 2, lc8 = (lane & 3) * 8;

    float4_t acc[2][4];
#pragma unroll
    for (int i = 0; i < 2; ++i)
#pragma unroll
        for (int j = 0; j < 4; ++j) acc[i][j] = (float4_t){0.f, 0.f, 0.f, 0.f};

    for (int k0 = 0; k0 < K; k0 += BK) {
        __syncthreads();
#pragma unroll
        for (int i = 0; i < 2; ++i) {
            const int ar = i * 64 + wave * 16;
            __builtin_amdgcn_global_load_lds(
                GLOBAL_AS(Ag + (size_t)(row0 + ar + lrow) * K + k0 + lc8),
                LDS_AS(&Ah[ar * BK]), 16, 0, 0);
        }
        {
            const int br = wave * 16;
            __builtin_amdgcn_global_load_lds(
                GLOBAL_AS(Bg + (size_t)(col0 + br + lrow) * K + k0 + lc8),
                LDS_AS(&Bh[br * BK]), 16, 0, 0);
        }
        __syncthreads();

        half8 af[2], bfr[4];
#pragma unroll
        for (int t = 0; t < 2; ++t)
            af[t] = *(const half8*)&Ah[(wave * 32 + t * 16 + l16) * BK + quad * 8];
#pragma unroll
        for (int t = 0; t < 4; ++t)
            bfr[t] = *(const half8*)&Bh[(t * 16 + l16) * BK + quad * 8];
#pragma unroll
        for (int i = 0; i < 2; ++i)
#pragma unroll
            for (int j = 0; j < 4; ++j)
                acc[i][j] = __builtin_amdgcn_mfma_f32_16x16x32_f16(af[i], bfr[j], acc[i][j], 0, 0, 0);
    }

#pragma unroll
    for (int i = 0; i < 2; ++i) {
#pragma unroll
        for (int j = 0; j < 4; ++j) {
            const int colb = col0 + j * 16 + l16;
            const float bv = bias[colb];
#pragma unroll
            for (int r = 0; r < 4; ++r) {
                const int row = row0 + wave * 32 + i * 16 + quad * 4 + r;
                C[(size_t)row * N + colb] = acc[i][j][r] + bv;
            }
        }
    }
}

// ---------------------------------------------------------------------------
// Chunk table: per head, 80 chunks of the causal k-space, heavy-first.
// Tile t (q-rows 128t..128t+127) needs 2t+2 k-tiles (64 keys each); chunked
// into ceil((t+1)/8) CONTIGUOUS chunks of up to 16 k-tiles at slot j:
// chunk j covers k-tiles [16j, 16j+L). entry = t | (j<<5) | (L<<7).
// Order: 52 full (L=16) by tile desc, then 28 remainders by length desc.
// ---------------------------------------------------------------------------
__device__ __constant__ unsigned short CHUNKS[80] = {
    2079, 2111, 2143, 2175,            // t=31 j0..3
    2078, 2110, 2142,                  // t=30 j0..2
    2077, 2109, 2141,                  // t=29
    2076, 2108, 2140,                  // t=28
    2075, 2107, 2139,                  // t=27
    2074, 2106, 2138,                  // t=26
    2073, 2105, 2137,                  // t=25
    2072, 2104, 2136,                  // t=24
    2071, 2103, 2135,                  // t=23
    2070, 2102,                        // t=22 j0..1
    2069, 2101,                        // t=21
    2068, 2100,                        // t=20
    2067, 2099,                        // t=19
    2066, 2098,                        // t=18
    2065, 2097,                        // t=17
    2064, 2096,                        // t=16
    2063, 2095,                        // t=15
    2062, 2061, 2060, 2059, 2058, 2057, 2056, 2055,  // t=14..7 j0
    1918, 1878, 1838, 1798,            // L=14: t=30j3,22j2,14j1,6j0
    1661, 1621, 1581, 1541,            // L=12
    1404, 1364, 1324, 1284,            // L=10
    1147, 1107, 1067, 1027,            // L=8
     890,  850,  810,  770,            // L=6
     633,  593,  553,  513,            // L=4
     376,  336,  296,  256             // L=2: t=24j3,16j2,8j1,0j0
};

// ---------------------------------------------------------------------------
// MFMA causal flash attention — EQUAL-CHUNK STREAM round.
// Round-7 post-mortem: 4-way modulo split REGRESSED (flash 67->90us):
// hbm_bytes 31->132MB (2x Q loads + stride-256 k-interleave killed L2
// locality + 2x partial writes) swamped the occupancy gain (24->35%).
// Round-6's defect was length VARIANCE (per-CU {1,16,16,...} decays
// concurrency 4->2), not split count. This round: fixed-size CONTIGUOUS
// chunks of 16 k-tiles -> 80 chunks/head -> 1280 blocks = EXACTLY 5/CU
// (LDS 32KB x 5 = 160KB cap), all co-resident, 20 waves/CU (5/SIMD).
// 65% of blocks are full 16-iters (79% of work at concurrency 5);
// remainders (2..14) dispatched last (heavy-first CHUNKS table).
// Contiguous k-ranges restore round-6 L2 locality; block count only
// 1.25x round 6 (Q/partial traffic ~20MB each, not 32+).
// Partial slot = chunk index j (0..3); nchunks derivable from row in
// combine -> no workspace init. Every existing chunk has >=1 unmasked
// k-tile for every wave (8j<=t -> kb0 <= q0+31) -> all l>0, no NaN.
// Inner loop IDENTICAL to rounds 6/7 (kb0=1024j, stride 64, count L):
// 64x64 K/V tiles DMA-staged into double-buffered XOR-swizzled LDS
// (slot(row,col8)=row*8+(col8^(row&7))), ONE __syncthreads per k-iter,
// S^T=K Q^T log2-domain, 31-fmax+1-shfl softmax, cvt_pkrtz+
// permlane32_swap P-exchange, defer-max (T13), setprio (T5), XCD-pinned
// heads h=(bid&7)*2+((bid>>3)&1).
// ---------------------------------------------------------------------------
__global__ __launch_bounds__(256, 5) void flash_attn_f16(
    const _Float16* __restrict__ qk, const _Float16* __restrict__ v_t,
    _Float16* __restrict__ opart, float* __restrict__ mlpart)
{
    __shared__ __align__(16) _Float16 KsT[2][64 * 64];   // [buf][slot*8]
    __shared__ __align__(16) _Float16 VtT[2][64 * 64];

    const int bid  = blockIdx.x;
    const int hv   = bid & 15;
    const int h    = (hv & 7) * 2 + (hv >> 3);  // XCD-pinned heads
    const int e    = CHUNKS[bid >> 4];          // heavy-first chunk
    const int tile = e & 31;
    const int jch  = (e >> 5) & 3;              // chunk/partial slot 0..3
    const int L    = e >> 7;                    // k-iters (1..16)

    const int wave = threadIdx.x >> 6;          // 0..3
    const int lane = threadIdx.x & 63;
    const int l31  = lane & 31;
    const int hi   = lane >> 5;                 // 0/1

    // DMA source-address components (lane's LDS slot is wave*128+p*64+lane):
    const int dma_r = wave * 16 + (lane >> 3);             // row  (+ p*8)
    const int dma_c = ((lane & 7) ^ (lane >> 3)) * 8;      // logical col (halfs)

    const _Float16* kplane = qk + 1024 + h * HDIM;
    const _Float16* vplane = v_t + (size_t)h * HDIM * 4096;

    const int q0 = tile * 128 + wave * 32;

    // ---- Q fragment (B-operand of 32x32x16): col=q=l31, k=16j+8*hi ------
    half8 qf[4];
#pragma unroll
    for (int jj = 0; jj < 4; ++jj)
        qf[jj] = *(const half8*)(qk + (size_t)(q0 + l31) * 2048 + h * HDIM
                                 + jj * 16 + hi * 8);

    float16_t o0 = (float16_t)0.f, o1 = (float16_t)0.f;
    float m_r = -INFINITY, l_r = 0.f;

    // ---- pre-stage first k-tile (kb0 = 1024*jch) into buf 0 ---------------
    const int kb0 = jch << 10;
#pragma unroll
    for (int p = 0; p < 2; ++p) {
        const int r = dma_r + p * 8;
        __builtin_amdgcn_global_load_lds(
            GLOBAL_AS(kplane + (size_t)(kb0 + r) * 2048 + dma_c),
            LDS_AS(&KsT[0][(wave * 128 + p * 64) * 8]), 16, 0, 0);
        __builtin_amdgcn_global_load_lds(
            GLOBAL_AS(vplane + (size_t)r * 4096 + kb0 + dma_c),
            LDS_AS(&VtT[0][(wave * 128 + p * 64) * 8]), 16, 0, 0);
    }

    int ib = 0;
    int kb = kb0;
    for (int it = 0; it < L; ++it, kb += 64, ib ^= 1) {
        __syncthreads();   // DMA(buf ib) done (vmcnt drain) + readers done

        if (it < L - 1) {  // async DMA of next k-tile into the other buf
            const int kn = kb + 64;
#pragma unroll
            for (int p = 0; p < 2; ++p) {
                const int r = dma_r + p * 8;
                __builtin_amdgcn_global_load_lds(
                    GLOBAL_AS(kplane + (size_t)(kn + r) * 2048 + dma_c),
                    LDS_AS(&KsT[ib ^ 1][(wave * 128 + p * 64) * 8]), 16, 0, 0);
                __builtin_amdgcn_global_load_lds(
                    GLOBAL_AS(vplane + (size_t)r * 4096 + kn + dma_c),
                    LDS_AS(&VtT[ib ^ 1][(wave * 128 + p * 64) * 8]), 16, 0, 0);
            }
        }

        // fully-masked trailing k-tiles (low waves): skip compute
        if (kb <= q0 + 31) {
            // ---- S^T = K Q^T (log2-domain logits), 2 key-chunks ----------
            float16_t s0 = (float16_t)0.f, s1 = (float16_t)0.f;
            __builtin_amdgcn_s_setprio(1);
#pragma unroll
            for (int jj = 0; jj < 4; ++jj) {
                const int r7 = l31 & 7;
                const half8 kf0 = *(const half8*)&KsT[ib][
                    ((l31) * 8 + ((2 * jj + hi) ^ r7)) * 8];
                const half8 kf1 = *(const half8*)&KsT[ib][
                    ((32 + l31) * 8 + ((2 * jj + hi) ^ r7)) * 8];
                s0 = __builtin_amdgcn_mfma_f32_32x32x16_f16(kf0, qf[jj], s0, 0, 0, 0);
                s1 = __builtin_amdgcn_mfma_f32_32x32x16_f16(kf1, qf[jj], s1, 0, 0, 0);
            }
            __builtin_amdgcn_s_setprio(0);

            // ---- causal mask (diagonal-straddling tile only) --------------
            if (kb + 63 > q0) {
                const int qg = q0 + l31;
#pragma unroll
                for (int gg = 0; gg < 4; ++gg)
#pragma unroll
                    for (int r = 0; r < 4; ++r) {
                        const int keyb = kb + r + 8 * gg + 4 * hi;
                        if (keyb > qg)      s0[4 * gg + r] = -INFINITY;
                        if (keyb + 32 > qg) s1[4 * gg + r] = -INFINITY;
                    }
            }

            // ---- online softmax: 31 fmax + ONE shfl, defer-max (T13) ------
            float mx = s0[0];
#pragma unroll
            for (int i = 1; i < 16; ++i) mx = fmaxf(mx, s0[i]);
#pragma unroll
            for (int i = 0; i < 16; ++i) mx = fmaxf(mx, s1[i]);
            mx = fmaxf(mx, __shfl_xor(mx, 32));
            const bool  grow  = mx > m_r + 8.0f;
            const float mnew  = grow ? mx : m_r;
            const float alpha = __builtin_amdgcn_exp2f(m_r - mnew); // 1 if !grow

            // ---- P = exp2(S - m), pack to fp16 words ----------------------
            int w0[8], w1[8];
            float lsum = 0.f;
#pragma unroll
            for (int i = 0; i < 8; ++i) {
                const float pa = __builtin_amdgcn_exp2f(s0[2 * i]     - mnew);
                const float pb = __builtin_amdgcn_exp2f(s0[2 * i + 1] - mnew);
                lsum += pa + pb;
                w0[i] = __builtin_bit_cast(int, __builtin_amdgcn_cvt_pkrtz(pa, pb));
            }
#pragma unroll
            for (int i = 0; i < 8; ++i) {
                const float pa = __builtin_amdgcn_exp2f(s1[2 * i]     - mnew);
                const float pb = __builtin_amdgcn_exp2f(s1[2 * i + 1] - mnew);
                lsum += pa + pb;
                w1[i] = __builtin_bit_cast(int, __builtin_amdgcn_cvt_pkrtz(pa, pb));
            }
            l_r = l_r * alpha + lsum;  // per-lane partial (alpha row-uniform)
            m_r = mnew;
            if (__any(grow)) {
#pragma unroll
                for (int i = 0; i < 16; ++i) { o0[i] *= alpha; o1[i] *= alpha; }
            }

            // ---- P -> B-operand frags via permlane32_swap (no LDS) --------
            half8 pf[4];
            {
                const int2_t a02 = __builtin_amdgcn_permlane32_swap(w0[0], w0[2], 0, 0);
                const int2_t a13 = __builtin_amdgcn_permlane32_swap(w0[1], w0[3], 0, 0);
                const int2_t a46 = __builtin_amdgcn_permlane32_swap(w0[4], w0[6], 0, 0);
                const int2_t a57 = __builtin_amdgcn_permlane32_swap(w0[5], w0[7], 0, 0);
                int4_t f0 = {a02[0], a13[0], a02[1], a13[1]};
                int4_t f1 = {a46[0], a57[0], a46[1], a57[1]};
                pf[0] = __builtin_bit_cast(half8, f0);
                pf[1] = __builtin_bit_cast(half8, f1);
                const int2_t b02 = __builtin_amdgcn_permlane32_swap(w1[0], w1[2], 0, 0);
                const int2_t b13 = __builtin_amdgcn_permlane32_swap(w1[1], w1[3], 0, 0);
                const int2_t b46 = __builtin_amdgcn_permlane32_swap(w1[4], w1[6], 0, 0);
                const int2_t b57 = __builtin_amdgcn_permlane32_swap(w1[5], w1[7], 0, 0);
                int4_t f2 = {b02[0], b13[0], b02[1], b13[1]};
                int4_t f3 = {b46[0], b57[0], b46[1], b57[1]};
                pf[2] = __builtin_bit_cast(half8, f2);
                pf[3] = __builtin_bit_cast(half8, f3);
            }

            // ---- O^T += V^T P^T -------------------------------------------
            __builtin_amdgcn_s_setprio(1);
#pragma unroll
            for (int kc = 0; kc < 4; ++kc) {
                const int r7 = l31 & 7;
                const half8 vf0 = *(const half8*)&VtT[ib][
                    ((l31) * 8 + ((2 * kc + hi) ^ r7)) * 8];
                const half8 vf1 = *(const half8*)&VtT[ib][
                    ((32 + l31) * 8 + ((2 * kc + hi) ^ r7)) * 8];
                o0 = __builtin_amdgcn_mfma_f32_32x32x16_f16(vf0, pf[kc], o0, 0, 0, 0);
                o1 = __builtin_amdgcn_mfma_f32_32x32x16_f16(vf1, pf[kc], o1, 0, 0, 0);
            }
            __builtin_amdgcn_s_setprio(0);
        } // active
    } // kb

    // ---- epilogue: store UNNORMALIZED partials + (m, l) at slot jch -------
    const float lr = l_r + __shfl_xor(l_r, 32);
    const size_t prow = (size_t)(jch * 4096 + q0 + l31);
#pragma unroll
    for (int gg = 0; gg < 4; ++gg) {
        half4 wa, wb;
#pragma unroll
        for (int r = 0; r < 4; ++r) {
            wa[r] = (_Float16)o0[4 * gg + r];
            wb[r] = (_Float16)o1[4 * gg + r];
        }
        const size_t base = prow * 1024 + h * HDIM + 8 * gg + 4 * hi;
        *(half4*)&opart[base]      = wa;
        *(half4*)&opart[base + 32] = wb;
    }
    if (hi == 0) {
        float2 ml; ml.x = m_r; ml.y = lr;
        ((float2*)mlpart)[prow * 16 + h] = ml;
    }
}

// ---------------------------------------------------------------------------
// combine: merge the row's nchunks partials per (row, head); write resh fp16.
// nchunks = ceil((tile+1)/8) is derivable from row -> no workspace init.
// 524288 threads, one half8 of d-values each.
// ---------------------------------------------------------------------------
__global__ __launch_bounds__(256) void combine(
    const _Float16* __restrict__ opart, const float* __restrict__ mlpart,
    _Float16* __restrict__ resh)
{
    const int idx = blockIdx.x * 256 + threadIdx.x;   // 0..524287
    const int row = idx >> 7;                          // 0..4095
    const int c8  = (idx & 127) * 8;                   // d-offset in the row
    const int h   = c8 >> 6;
    const int nch = ((row >> 7) + 8) >> 3;             // 1..4 chunks
    float2 ml[4];
    float m = -INFINITY;
    for (int s = 0; s < nch; ++s) {
        ml[s] = ((const float2*)mlpart)[(size_t)(s * 4096 + row) * 16 + h];
        m = fmaxf(m, ml[s].x);
    }
    float a[4], lsum = 0.f;
    for (int s = 0; s < nch; ++s) {
        a[s] = __builtin_amdgcn_exp2f(ml[s].x - m);
        lsum += ml[s].y * a[s];
    }
    const float inv = 1.0f / lsum;                     // every chunk has l>0
    float acc[8];
#pragma unroll
    for (int jj = 0; jj < 8; ++jj) acc[jj] = 0.f;
    for (int s = 0; s < nch; ++s) {
        const half8 os = *(const half8*)&opart[(size_t)(s * 4096 + row) * 1024 + c8];
#pragma unroll
        for (int jj = 0; jj < 8; ++jj) acc[jj] += (float)os[jj] * a[s];
    }
    half8 w;
#pragma unroll
    for (int jj = 0; jj < 8; ++jj) w[jj] = (_Float16)(acc[jj] * inv);
    *(half8*)&resh[(size_t)row * 1024 + c8] = w;
}

// ---------------------------------------------------------------------------
// launch
// ---------------------------------------------------------------------------
extern "C" void kernel_launch(void* const* d_in, const int* in_sizes, int n_in,
                              void* d_out, int out_size, void* d_ws, size_t ws_size,
                              hipStream_t stream)
{
    const float* x    = (const float*)d_in[0];
    const float* Wqkv = (const float*)d_in[2];
    const float* bqkv = (const float*)d_in[3];
    const float* Wp   = (const float*)d_in[4];
    const float* bp   = (const float*)d_in[5];
    float* out = (float*)d_out;

    _Float16* xh  = (_Float16*)d_ws;                 // [4096,1024] fp16  8MB
    _Float16* WTh = xh + (size_t)4096 * 1024;        // [3072,1024] fp16  6MB
    _Float16* qkh = WTh + (size_t)3072 * 1024;       // [4096,2048] fp16 16MB
    _Float16* vtg = qkh + (size_t)4096 * 2048;       // V^T [1024,4096]   8MB
    _Float16* WpT = vtg + (size_t)1024 * 4096;       // [1024,1024] fp16  2MB
    _Float16* opart = WpT + (size_t)1024 * 1024;     // [4,4096,1024] fp16 32MB
    float* mlpart = (float*)(opart + (size_t)4 * 4096 * 1024);  // [4,4096,16,2] f32 2MB
    _Float16* resh = xh;            // alias: x fp16 dead after QKV GEMM

    dim3 blk(256);

    prep<<<dim3(5120), blk, 0, stream>>>(x, Wqkv, Wp, xh, WTh, WpT);

    gemm_qkv<<<dim3(3072 / 128, 4096 / 128), blk, 0, stream>>>(
        xh, WTh, bqkv, qkh, vtg, 1024);

    flash_attn_f16<<<dim3(1280), dim3(256), 0, stream>>>(qkh, vtg, opart, mlpart);

    combine<<<dim3(2048), blk, 0, stream>>>(opart, mlpart, resh);

    gemm_out<<<dim3(1024 / 64, 4096 / 128), blk, 0, stream>>>(
        resh, WpT, bp, out, 1024, 1024);
}

// Round 9
// 251.424 us; speedup vs baseline: 1.1864x; 1.1864x over previous
//
#include <hip/hip_runtime.h>
#include <hip/hip_bf16.h>
#include <math.h>

#define S_LEN 4096
#define EMB   1024
#define NHEAD 16
#define HDIM  64

typedef __attribute__((ext_vector_type(8))) _Float16 half8;
typedef __attribute__((ext_vector_type(4))) _Float16 half4;
typedef __attribute__((ext_vector_type(4))) float float4_t;
typedef __attribute__((ext_vector_type(16))) float float16_t;
typedef __attribute__((ext_vector_type(4))) int int4_t;
typedef __attribute__((ext_vector_type(2))) int int2_t;

#define GLOBAL_AS(p) ((const __attribute__((address_space(1))) void*)(p))
#define LDS_AS(p)    ((__attribute__((address_space(3))) void*)(p))

#define LOG2E 1.4426950408889634f

// ---------------------------------------------------------------------------
// fused prep: blocks [0,4096) convert x fp32->fp16; [4096,4864) transpose
// Wqkv [1024,3072] -> WTh [3072,1024]; [4864,5120) transpose Wp -> WpT.
// ---------------------------------------------------------------------------
__global__ __launch_bounds__(256) void prep(
    const float* __restrict__ x, const float* __restrict__ Wqkv,
    const float* __restrict__ Wp,
    _Float16* __restrict__ xh, _Float16* __restrict__ WTh,
    _Float16* __restrict__ WpT)
{
    const int bid = blockIdx.x;
    if (bid < 4096) {
        const int i = bid * 256 + threadIdx.x;
        const float4_t v = ((const float4_t*)x)[i];
        half4 hh;
#pragma unroll
        for (int j = 0; j < 4; ++j) hh[j] = (_Float16)v[j];
        ((half4*)xh)[i] = hh;
        return;
    }
    __shared__ float t[64][65];
    const float* in;
    _Float16* out;
    int R, C, bx, by;
    if (bid < 4096 + 768) {
        const int idx = bid - 4096;
        bx = idx % 48; by = idx / 48;
        in = Wqkv; out = WTh; R = 1024; C = 3072;
    } else {
        const int idx = bid - 4864;
        bx = idx & 15; by = idx >> 4;
        in = Wp; out = WpT; R = 1024; C = 1024;
    }
    const int r0 = by * 64, c0 = bx * 64;
    for (int i = threadIdx.x; i < 64 * 64; i += 256) {
        int r = i >> 6, c = i & 63;
        t[r][c] = in[(size_t)(r0 + r) * C + c0 + c];
    }
    __syncthreads();
    for (int i = threadIdx.x; i < 64 * 64; i += 256) {
        int c = i >> 6, r = i & 63;
        out[(size_t)(c0 + c) * R + r0 + r] = (_Float16)t[r][c];
    }
}

// ---------------------------------------------------------------------------
// QKV GEMM, plain fp16, m97 structure: 128x128 tile, BK=32, global_load_lds.
// This round: XCD-bijective block swizzle (T1) — grid 24x32 = 768 = 96/XCD,
// each XCD gets a contiguous 4-row span of tiles (B-panel reuse in L2).
// Epilogue: cols<1024 -> q plane; 1024..2047 -> k plane SCALED by log2(e);
// cols>=2048 -> fp16 V^T [1024,4096], packed half4 along s.
// ---------------------------------------------------------------------------
__global__ __launch_bounds__(256) void gemm_qkv(
    const _Float16* __restrict__ Ag, const _Float16* __restrict__ Bg,
    const float* __restrict__ bias,
    _Float16* __restrict__ qk, _Float16* __restrict__ vt, int K)
{
    constexpr int BK = 32;
    __shared__ _Float16 Ah[128 * BK];
    __shared__ _Float16 Bh[128 * BK];

    const int tid = threadIdx.x;
    const int wave = tid >> 6, lane = tid & 63;
    const int l16 = lane & 15, quad = lane >> 4;
    const int wr = wave >> 1, wc = wave & 1;
    const int lid = blockIdx.y * 24 + blockIdx.x;      // 0..767
    const int swz = (lid & 7) * 96 + (lid >> 3);       // bijective (768%8==0)
    const int row0 = (swz / 24) * 128, col0 = (swz % 24) * 128;
    const int lrow = lane >> 2, lc8 = (lane & 3) * 8;

    float4_t acc[4][4];
#pragma unroll
    for (int i = 0; i < 4; ++i)
#pragma unroll
        for (int j = 0; j < 4; ++j) acc[i][j] = (float4_t){0.f, 0.f, 0.f, 0.f};

    for (int k0 = 0; k0 < K; k0 += BK) {
        __syncthreads();
#pragma unroll
        for (int i = 0; i < 2; ++i) {
            const int ar = i * 64 + wave * 16;
            __builtin_amdgcn_global_load_lds(
                GLOBAL_AS(Ag + (size_t)(row0 + ar + lrow) * K + k0 + lc8),
                LDS_AS(&Ah[ar * BK]), 16, 0, 0);
            __builtin_amdgcn_global_load_lds(
                GLOBAL_AS(Bg + (size_t)(col0 + ar + lrow) * K + k0 + lc8),
                LDS_AS(&Bh[ar * BK]), 16, 0, 0);
        }
        __syncthreads();

        half8 af[4], bfr[4];
#pragma unroll
        for (int t = 0; t < 4; ++t) {
            af[t]  = *(const half8*)&Ah[(wr * 64 + t * 16 + l16) * BK + quad * 8];
            bfr[t] = *(const half8*)&Bh[(wc * 64 + t * 16 + l16) * BK + quad * 8];
        }
#pragma unroll
        for (int i = 0; i < 4; ++i)
#pragma unroll
            for (int j = 0; j < 4; ++j)
                acc[i][j] = __builtin_amdgcn_mfma_f32_16x16x32_f16(af[i], bfr[j], acc[i][j], 0, 0, 0);
    }

#pragma unroll
    for (int i = 0; i < 4; ++i) {
#pragma unroll
        for (int j = 0; j < 4; ++j) {
            const int colb = col0 + wc * 64 + j * 16 + l16;
            const float bv = bias[colb];
            const int rowb = row0 + wr * 64 + i * 16 + quad * 4;
            if (colb < 2048) {
                const float sc = (colb >= 1024) ? LOG2E : 1.0f;
#pragma unroll
                for (int r = 0; r < 4; ++r)
                    qk[(size_t)(rowb + r) * 2048 + colb] =
                        (_Float16)((acc[i][j][r] + bv) * sc);
            } else {
                half4 w;
#pragma unroll
                for (int r = 0; r < 4; ++r) w[r] = (_Float16)(acc[i][j][r] + bv);
                *(half4*)&vt[(size_t)(colb - 2048) * 4096 + rowb] = w;
            }
        }
    }
}

// ---------------------------------------------------------------------------
// Out-projection GEMM, fp16, 128(M)x64(N) tile -> 512 blocks (2/CU).
// XCD-bijective swizzle added (512%8==0, 64 blocks/XCD contiguous span).
// ---------------------------------------------------------------------------
__global__ __launch_bounds__(256) void gemm_out(
    const _Float16* __restrict__ Ag, const _Float16* __restrict__ Bg,
    const float* __restrict__ bias, float* __restrict__ C, int N, int K)
{
    constexpr int BK = 32;
    __shared__ _Float16 Ah[128 * BK];
    __shared__ _Float16 Bh[64 * BK];

    const int tid = threadIdx.x;
    const int wave = tid >> 6, lane = tid & 63;
    const int l16 = lane & 15, quad = lane >> 4;
    const int lid = blockIdx.y * 16 + blockIdx.x;      // 0..511
    const int swz = (lid & 7) * 64 + (lid >> 3);       // bijective (512%8==0)
    const int row0 = (swz / 16) * 128, col0 = (swz % 16) * 64;
    const int lrow = lane >> 2, lc8 = (lane & 3) * 8;

    float4_t acc[2][4];
#pragma unroll
    for (int i = 0; i < 2; ++i)
#pragma unroll
        for (int j = 0; j < 4; ++j) acc[i][j] = (float4_t){0.f, 0.f, 0.f, 0.f};

    for (int k0 = 0; k0 < K; k0 += BK) {
        __syncthreads();
#pragma unroll
        for (int i = 0; i < 2; ++i) {
            const int ar = i * 64 + wave * 16;
            __builtin_amdgcn_global_load_lds(
                GLOBAL_AS(Ag + (size_t)(row0 + ar + lrow) * K + k0 + lc8),
                LDS_AS(&Ah[ar * BK]), 16, 0, 0);
        }
        {
            const int br = wave * 16;
            __builtin_amdgcn_global_load_lds(
                GLOBAL_AS(Bg + (size_t)(col0 + br + lrow) * K + k0 + lc8),
                LDS_AS(&Bh[br * BK]), 16, 0, 0);
        }
        __syncthreads();

        half8 af[2], bfr[4];
#pragma unroll
        for (int t = 0; t < 2; ++t)
            af[t] = *(const half8*)&Ah[(wave * 32 + t * 16 + l16) * BK + quad * 8];
#pragma unroll
        for (int t = 0; t < 4; ++t)
            bfr[t] = *(const half8*)&Bh[(t * 16 + l16) * BK + quad * 8];
#pragma unroll
        for (int i = 0; i < 2; ++i)
#pragma unroll
            for (int j = 0; j < 4; ++j)
                acc[i][j] = __builtin_amdgcn_mfma_f32_16x16x32_f16(af[i], bfr[j], acc[i][j], 0, 0, 0);
    }

#pragma unroll
    for (int i = 0; i < 2; ++i) {
#pragma unroll
        for (int j = 0; j < 4; ++j) {
            const int colb = col0 + j * 16 + l16;
            const float bv = bias[colb];
#pragma unroll
            for (int r = 0; r < 4; ++r) {
                const int row = row0 + wave * 32 + i * 16 + quad * 4 + r;
                C[(size_t)row * N + colb] = acc[i][j][r] + bv;
            }
        }
    }
}

// ---------------------------------------------------------------------------
// MFMA causal flash attention — UNIFORM PAIRED-CHUNK round.
// Round-7/8 post-mortem: both oversubscription schemes hit traffic walls
// (R7: stride-256 interleave, FETCH 42MB; R8: 5-way disjoint-offset chunk
// mix thrashing the 4MB XCD L2, hbm 92MB). Round-6 (66.9us) defect was
// CONCURRENCY DECAY: per-CU lengths {j+1,j+1,32-j,32-j} -> 4 resident
// blocks decay to 2 for most of the makespan.
// This round: every block has UNIFORM length. Block (pair p, slot s)
// sequentially runs chunk s of tile p, then chunk s of tile 31-p, where
// chunk s of tile t covers CONTIGUOUS k-tiles [s*Nt/4, (s+1)*Nt/4),
// Nt = 2t+2. Pair length = 16-17 iters for EVERY block -> 1024 blocks,
// 4/CU resident (LDS 32KB), concurrency 4 sustained end-to-end.
// Traffic ~= round 6 + Q x2 + partials x2 (~+6us), contiguous k-ranges.
// Chunks with L=0 (t=0 edge) store m=-inf, l=0 -> zero combine weight.
// Inner loop IDENTICAL to rounds 5-8: 64x64 K/V tiles DMA-staged into
// double-buffered XOR-swizzled LDS (slot(row,col8)=row*8+(col8^(row&7))),
// ONE __syncthreads per k-iter, S^T=K Q^T log2-domain, 31-fmax+1-shfl
// softmax, cvt_pkrtz+permlane32_swap P-exchange, defer-max (T13),
// setprio (T5), XCD-pinned heads h=(bid&7)*2+((bid>>3)&1).
// ---------------------------------------------------------------------------
__global__ __launch_bounds__(256, 4) void flash_attn_f16(
    const _Float16* __restrict__ qk, const _Float16* __restrict__ v_t,
    _Float16* __restrict__ opart, float* __restrict__ mlpart)
{
    __shared__ __align__(16) _Float16 KsT[2][64 * 64];   // [buf][slot*8]
    __shared__ __align__(16) _Float16 VtT[2][64 * 64];

    const int bid  = blockIdx.x;
    const int hv   = bid & 15;
    const int h    = (hv & 7) * 2 + (hv >> 3);  // XCD-pinned heads
    const int pp   = (bid >> 4) & 15;           // pair 0..15
    const int sch  = bid >> 8;                  // chunk slot 0..3

    const int wave = threadIdx.x >> 6;          // 0..3
    const int lane = threadIdx.x & 63;
    const int l31  = lane & 31;
    const int hi   = lane >> 5;                 // 0/1

    // DMA source-address components (lane's LDS slot is wave*128+p*64+lane):
    const int dma_r = wave * 16 + (lane >> 3);             // row  (+ p*8)
    const int dma_c = ((lane & 7) ^ (lane >> 3)) * 8;      // logical col (halfs)

    const _Float16* kplane = qk + 1024 + h * HDIM;
    const _Float16* vplane = v_t + (size_t)h * HDIM * 4096;

    for (int ph = 0; ph < 2; ++ph) {
        const int tile = ph ? (31 - pp) : pp;
        const int Nt   = 2 * tile + 2;
        const int c0   = (sch * Nt) >> 2;
        const int L    = (((sch + 1) * Nt) >> 2) - c0;     // 0..16 k-iters
        const int q0   = tile * 128 + wave * 32;

        // ---- Q fragment (B-operand of 32x32x16): col=q=l31, k=16j+8*hi ----
        half8 qf[4];
#pragma unroll
        for (int jj = 0; jj < 4; ++jj)
            qf[jj] = *(const half8*)(qk + (size_t)(q0 + l31) * 2048 + h * HDIM
                                     + jj * 16 + hi * 8);

        float16_t o0 = (float16_t)0.f, o1 = (float16_t)0.f;
        float m_r = -INFINITY, l_r = 0.f;

        if (L > 0) {
            // ---- pre-stage first k-tile into buf 0 (protect prev readers) -
            const int kb0 = c0 * 64;
            __syncthreads();
#pragma unroll
            for (int p = 0; p < 2; ++p) {
                const int r = dma_r + p * 8;
                __builtin_amdgcn_global_load_lds(
                    GLOBAL_AS(kplane + (size_t)(kb0 + r) * 2048 + dma_c),
                    LDS_AS(&KsT[0][(wave * 128 + p * 64) * 8]), 16, 0, 0);
                __builtin_amdgcn_global_load_lds(
                    GLOBAL_AS(vplane + (size_t)r * 4096 + kb0 + dma_c),
                    LDS_AS(&VtT[0][(wave * 128 + p * 64) * 8]), 16, 0, 0);
            }

            int ib = 0;
            int kb = kb0;
            for (int it = 0; it < L; ++it, kb += 64, ib ^= 1) {
                __syncthreads();   // DMA(buf ib) done + readers done

                if (it < L - 1) {  // async DMA of next k-tile into other buf
                    const int kn = kb + 64;
#pragma unroll
                    for (int p = 0; p < 2; ++p) {
                        const int r = dma_r + p * 8;
                        __builtin_amdgcn_global_load_lds(
                            GLOBAL_AS(kplane + (size_t)(kn + r) * 2048 + dma_c),
                            LDS_AS(&KsT[ib ^ 1][(wave * 128 + p * 64) * 8]), 16, 0, 0);
                        __builtin_amdgcn_global_load_lds(
                            GLOBAL_AS(vplane + (size_t)r * 4096 + kn + dma_c),
                            LDS_AS(&VtT[ib ^ 1][(wave * 128 + p * 64) * 8]), 16, 0, 0);
                    }
                }

                // fully-masked k-tile for this wave: skip compute
                if (kb <= q0 + 31) {
                    // ---- S^T = K Q^T (log2-domain logits), 2 key-chunks ---
                    float16_t s0 = (float16_t)0.f, s1 = (float16_t)0.f;
                    __builtin_amdgcn_s_setprio(1);
#pragma unroll
                    for (int jj = 0; jj < 4; ++jj) {
                        const int r7 = l31 & 7;
                        const half8 kf0 = *(const half8*)&KsT[ib][
                            ((l31) * 8 + ((2 * jj + hi) ^ r7)) * 8];
                        const half8 kf1 = *(const half8*)&KsT[ib][
                            ((32 + l31) * 8 + ((2 * jj + hi) ^ r7)) * 8];
                        s0 = __builtin_amdgcn_mfma_f32_32x32x16_f16(kf0, qf[jj], s0, 0, 0, 0);
                        s1 = __builtin_amdgcn_mfma_f32_32x32x16_f16(kf1, qf[jj], s1, 0, 0, 0);
                    }
                    __builtin_amdgcn_s_setprio(0);

                    // ---- causal mask (diagonal-straddling tile only) ------
                    if (kb + 63 > q0) {
                        const int qg = q0 + l31;
#pragma unroll
                        for (int gg = 0; gg < 4; ++gg)
#pragma unroll
                            for (int r = 0; r < 4; ++r) {
                                const int keyb = kb + r + 8 * gg + 4 * hi;
                                if (keyb > qg)      s0[4 * gg + r] = -INFINITY;
                                if (keyb + 32 > qg) s1[4 * gg + r] = -INFINITY;
                            }
                    }

                    // ---- online softmax: 31 fmax + ONE shfl, defer-max ----
                    float mx = s0[0];
#pragma unroll
                    for (int i = 1; i < 16; ++i) mx = fmaxf(mx, s0[i]);
#pragma unroll
                    for (int i = 0; i < 16; ++i) mx = fmaxf(mx, s1[i]);
                    mx = fmaxf(mx, __shfl_xor(mx, 32));
                    const bool  grow  = mx > m_r + 8.0f;
                    const float mnew  = grow ? mx : m_r;
                    const float alpha = __builtin_amdgcn_exp2f(m_r - mnew); // 1 if !grow

                    // ---- P = exp2(S - m), pack to fp16 words --------------
                    int w0[8], w1[8];
                    float lsum = 0.f;
#pragma unroll
                    for (int i = 0; i < 8; ++i) {
                        const float pa = __builtin_amdgcn_exp2f(s0[2 * i]     - mnew);
                        const float pb = __builtin_amdgcn_exp2f(s0[2 * i + 1] - mnew);
                        lsum += pa + pb;
                        w0[i] = __builtin_bit_cast(int, __builtin_amdgcn_cvt_pkrtz(pa, pb));
                    }
#pragma unroll
                    for (int i = 0; i < 8; ++i) {
                        const float pa = __builtin_amdgcn_exp2f(s1[2 * i]     - mnew);
                        const float pb = __builtin_amdgcn_exp2f(s1[2 * i + 1] - mnew);
                        lsum += pa + pb;
                        w1[i] = __builtin_bit_cast(int, __builtin_amdgcn_cvt_pkrtz(pa, pb));
                    }
                    l_r = l_r * alpha + lsum;  // per-lane partial
                    m_r = mnew;
                    if (__any(grow)) {
#pragma unroll
                        for (int i = 0; i < 16; ++i) { o0[i] *= alpha; o1[i] *= alpha; }
                    }

                    // ---- P -> B-operand frags via permlane32_swap ---------
                    half8 pf[4];
                    {
                        const int2_t a02 = __builtin_amdgcn_permlane32_swap(w0[0], w0[2], 0, 0);
                        const int2_t a13 = __builtin_amdgcn_permlane32_swap(w0[1], w0[3], 0, 0);
                        const int2_t a46 = __builtin_amdgcn_permlane32_swap(w0[4], w0[6], 0, 0);
                        const int2_t a57 = __builtin_amdgcn_permlane32_swap(w0[5], w0[7], 0, 0);
                        int4_t f0 = {a02[0], a13[0], a02[1], a13[1]};
                        int4_t f1 = {a46[0], a57[0], a46[1], a57[1]};
                        pf[0] = __builtin_bit_cast(half8, f0);
                        pf[1] = __builtin_bit_cast(half8, f1);
                        const int2_t b02 = __builtin_amdgcn_permlane32_swap(w1[0], w1[2], 0, 0);
                        const int2_t b13 = __builtin_amdgcn_permlane32_swap(w1[1], w1[3], 0, 0);
                        const int2_t b46 = __builtin_amdgcn_permlane32_swap(w1[4], w1[6], 0, 0);
                        const int2_t b57 = __builtin_amdgcn_permlane32_swap(w1[5], w1[7], 0, 0);
                        int4_t f2 = {b02[0], b13[0], b02[1], b13[1]};
                        int4_t f3 = {b46[0], b57[0], b46[1], b57[1]};
                        pf[2] = __builtin_bit_cast(half8, f2);
                        pf[3] = __builtin_bit_cast(half8, f3);
                    }

                    // ---- O^T += V^T P^T -----------------------------------
                    __builtin_amdgcn_s_setprio(1);
#pragma unroll
                    for (int kc = 0; kc < 4; ++kc) {
                        const int r7 = l31 & 7;
                        const half8 vf0 = *(const half8*)&VtT[ib][
                            ((l31) * 8 + ((2 * kc + hi) ^ r7)) * 8];
                        const half8 vf1 = *(const half8*)&VtT[ib][
                            ((32 + l31) * 8 + ((2 * kc + hi) ^ r7)) * 8];
                        o0 = __builtin_amdgcn_mfma_f32_32x32x16_f16(vf0, pf[kc], o0, 0, 0, 0);
                        o1 = __builtin_amdgcn_mfma_f32_32x32x16_f16(vf1, pf[kc], o1, 0, 0, 0);
                    }
                    __builtin_amdgcn_s_setprio(0);
                } // active
            } // kb
        } // L > 0

        // ---- epilogue: store UNNORMALIZED partials + (m, l) at slot sch ---
        const float lr = l_r + __shfl_xor(l_r, 32);
        const size_t prow = (size_t)(sch * 4096 + q0 + l31);
#pragma unroll
        for (int gg = 0; gg < 4; ++gg) {
            half4 wa, wb;
#pragma unroll
            for (int r = 0; r < 4; ++r) {
                wa[r] = (_Float16)o0[4 * gg + r];
                wb[r] = (_Float16)o1[4 * gg + r];
            }
            const size_t base = prow * 1024 + h * HDIM + 8 * gg + 4 * hi;
            *(half4*)&opart[base]      = wa;
            *(half4*)&opart[base + 32] = wb;
        }
        if (hi == 0) {
            float2 ml; ml.x = m_r; ml.y = lr;
            ((float2*)mlpart)[prow * 16 + h] = ml;
        }
    } // ph
}

// ---------------------------------------------------------------------------
// combine: merge the FOUR chunk partials per (row, head); write resh fp16.
// Empty chunks stored m=-inf, l=0 -> weight exp2(-inf-m)=0. Chunk 0 (or the
// first nonempty) always has l>0 for every row -> no div-by-0.
// 524288 threads, one half8 of d-values each.
// ---------------------------------------------------------------------------
__global__ __launch_bounds__(256) void combine(
    const _Float16* __restrict__ opart, const float* __restrict__ mlpart,
    _Float16* __restrict__ resh)
{
    const int idx = blockIdx.x * 256 + threadIdx.x;   // 0..524287
    const int row = idx >> 7;                          // 0..4095
    const int c8  = (idx & 127) * 8;                   // d-offset in the row
    const int h   = c8 >> 6;
    float2 ml[4];
    float m = -INFINITY;
#pragma unroll
    for (int s = 0; s < 4; ++s) {
        ml[s] = ((const float2*)mlpart)[(size_t)(s * 4096 + row) * 16 + h];
        m = fmaxf(m, ml[s].x);
    }
    float a[4], lsum = 0.f;
#pragma unroll
    for (int s = 0; s < 4; ++s) {
        a[s] = __builtin_amdgcn_exp2f(ml[s].x - m);
        lsum += ml[s].y * a[s];
    }
    const float inv = 1.0f / lsum;
    float acc[8];
#pragma unroll
    for (int jj = 0; jj < 8; ++jj) acc[jj] = 0.f;
#pragma unroll
    for (int s = 0; s < 4; ++s) {
        const half8 os = *(const half8*)&opart[(size_t)(s * 4096 + row) * 1024 + c8];
#pragma unroll
        for (int jj = 0; jj < 8; ++jj) acc[jj] += (float)os[jj] * a[s];
    }
    half8 w;
#pragma unroll
    for (int jj = 0; jj < 8; ++jj) w[jj] = (_Float16)(acc[jj] * inv);
    *(half8*)&resh[(size_t)row * 1024 + c8] = w;
}

// ---------------------------------------------------------------------------
// launch
// ---------------------------------------------------------------------------
extern "C" void kernel_launch(void* const* d_in, const int* in_sizes, int n_in,
                              void* d_out, int out_size, void* d_ws, size_t ws_size,
                              hipStream_t stream)
{
    const float* x    = (const float*)d_in[0];
    const float* Wqkv = (const float*)d_in[2];
    const float* bqkv = (const float*)d_in[3];
    const float* Wp   = (const float*)d_in[4];
    const float* bp   = (const float*)d_in[5];
    float* out = (float*)d_out;

    _Float16* xh  = (_Float16*)d_ws;                 // [4096,1024] fp16  8MB
    _Float16* WTh = xh + (size_t)4096 * 1024;        // [3072,1024] fp16  6MB
    _Float16* qkh = WTh + (size_t)3072 * 1024;       // [4096,2048] fp16 16MB
    _Float16* vtg = qkh + (size_t)4096 * 2048;       // V^T [1024,4096]   8MB
    _Float16* WpT = vtg + (size_t)1024 * 4096;       // [1024,1024] fp16  2MB
    _Float16* opart = WpT + (size_t)1024 * 1024;     // [4,4096,1024] fp16 32MB
    float* mlpart = (float*)(opart + (size_t)4 * 4096 * 1024);  // [4,4096,16,2] f32 2MB
    _Float16* resh = xh;            // alias: x fp16 dead after QKV GEMM

    dim3 blk(256);

    prep<<<dim3(5120), blk, 0, stream>>>(x, Wqkv, Wp, xh, WTh, WpT);

    gemm_qkv<<<dim3(3072 / 128, 4096 / 128), blk, 0, stream>>>(
        xh, WTh, bqkv, qkh, vtg, 1024);

    flash_attn_f16<<<dim3(1024), dim3(256), 0, stream>>>(qkh, vtg, opart, mlpart);

    combine<<<dim3(2048), blk, 0, stream>>>(opart, mlpart, resh);

    gemm_out<<<dim3(1024 / 64, 4096 / 128), blk, 0, stream>>>(
        resh, WpT, bp, out, 1024, 1024);
}